// Round 24
// baseline (174.452 us; speedup 1.0000x reference)
//
#include <hip/hip_runtime.h>

#define Bb 8
#define Nn 2048
#define Dd 512

#define KV2 64           // keys per tile/image
#define NT2 32           // images per batch
#define SPS2 76          // sP row stride (u16): 152B -> 2-way on af reads

// fallback (no ws): R10 structure
#define KVF 64
#define NTF (Nn / KVF)
#define PPF 72

typedef __attribute__((ext_vector_type(8))) short bf8;
typedef __attribute__((ext_vector_type(4))) float f4;
typedef __attribute__((ext_vector_type(16))) float f16v;
struct __align__(16) U8 { unsigned short s[8]; };
struct __align__(8) US4 { unsigned short s[4]; };

__device__ __forceinline__ unsigned short f2bf(float f) {
  union { float f; unsigned u; } v; v.f = f;
  unsigned r = v.u + 0x7fffu + ((v.u >> 16) & 1u);
  return (unsigned short)(r >> 16);
}
__device__ __forceinline__ float bf2f(unsigned short h) {
  union { unsigned u; float f; } v; v.u = ((unsigned)h) << 16; return v.f;
}

// async global->LDS, 16B per lane; LDS dest = wave-uniform base + lane*16
__device__ __forceinline__ void gload_lds16(const unsigned short* g, unsigned short* l) {
  __builtin_amdgcn_global_load_lds(
      (const __attribute__((address_space(1))) void*)g,
      (__attribute__((address_space(3))) void*)l, 16, 0, 0);
}

// ---------------------------------------------------------------------------
// Build per-(b,tile) FRAGMENT-MAJOR images for the 32x32x16 key-split path.
// Image = [K 64 frags | V 64 frags] x 1 KB = 128 KB per (b, 64-key tile).
// K frag fk (0..63), lane L: element ( key = (fk>>5)*32 + (L&31),
//   d = (fk&31)*16 + (L>>5)*8 + e ) at u16 offset (fk*64 + L)*8 + e.
// V frag fv (0..63), lane L: element ( d = (fv>>2)*32 + (L&31),
//   key = (fv&3)*16 + (L>>5)*8 + e ) at 32768 + (fv*64 + L)*8 + e.
// All kernel-side frag reads are contiguous 1 KB wave bursts.
// ---------------------------------------------------------------------------
__global__ __launch_bounds__(256)
void build_images(const float* __restrict__ X, unsigned short* __restrict__ W) {
  __shared__ unsigned short sT[KV2 * Dd];  // 64 keys x 512 d bf16 = 64 KB
  const int t = blockIdx.x, b = blockIdx.y, tid = threadIdx.x;
  const float* src = X + ((size_t)b * Nn + t * KV2) * Dd;
#pragma unroll
  for (int i = 0; i < 32; ++i) {
    int idx = i * 256 + tid;                 // float4 index, 0..8191
    float4 v = *(const float4*)(src + idx * 4);
    US4 hx;
    hx.s[0] = f2bf(v.x); hx.s[1] = f2bf(v.y);
    hx.s[2] = f2bf(v.z); hx.s[3] = f2bf(v.w);
    *(US4*)(sT + idx * 4) = hx;
  }
  __syncthreads();
  unsigned short* img = W + ((size_t)(b * NT2 + t) << 16);
  // K frags (contiguous 16B reads from sT)
#pragma unroll
  for (int i = 0; i < 16; ++i) {
    int slot = i * 256 + tid;                // fk*64 + L, 0..4095
    int fk = slot >> 6, L = slot & 63;
    int key = (fk >> 5) * 32 + (L & 31);
    int d0 = (fk & 31) * 16 + (L >> 5) * 8;
    U8 v = *(const U8*)(sT + key * Dd + d0);
    *(U8*)(img + slot * 8) = v;
  }
  // V frags (transposed gather)
#pragma unroll
  for (int i = 0; i < 16; ++i) {
    int slot = i * 256 + tid;
    int fv = slot >> 6, L = slot & 63;
    int d = (fv >> 2) * 32 + (L & 31);
    int k0 = (fv & 3) * 16 + (L >> 5) * 8;
    U8 v;
#pragma unroll
    for (int e = 0; e < 8; ++e) v.s[e] = sT[(k0 + e) * Dd + d];
    *(U8*)(img + 32768 + slot * 8) = v;
  }
}

// ---------------------------------------------------------------------------
// Key-split 32x32x16 attention. 512 thr = 8 waves. Block = 64 q-rows, KV2=64.
// QK^T role (qg = w>>2, kb = (w>>1)&1, dh = w&1): S[32q(qg) x 32k(kb)] partial
//   over d-half dh (16 MFMAs; qf[16] persistent = 64 VGPR).
// Exchange: single partner-sum (write 16 bf16 -> barA -> read my 8, add).
// Softmax: NO-max (p = exp(s*scale*mask); wave-local, rows split 8/8 between
//   dh partners -> 8 exps/wave per 64 keys, no replication). P -> sP once.
// PV role (qg, dq = w&3): af[4] from sP (barB), 16 V-frags from L2 (R22:
//   L2 == LDS for V), 4 ones-MFMAs for row-sums, 16 PV MFMAs.
// K images double-buffered (2x64 KB), prefetch issued after barB -> drains at
// barC under PV cover. 3 barriers/tile x 32 tiles = 96 crossings (vs 128).
// ---------------------------------------------------------------------------
__global__ __launch_bounds__(512, 1)
void attn64(const unsigned short* __restrict__ W, const int* __restrict__ mask,
            float* __restrict__ out) {
  __shared__ unsigned short sK[2][32768];           // 2 x 64 KB K images
  __shared__ unsigned short sSx[2][2][2][16][64];   // 16 KB partial exchange
  __shared__ unsigned short sP[2][32][SPS2];        // 9.5 KB P (per qg)

  const int tid  = threadIdx.x;
  const int wave = tid >> 6;
  const int qg = wave >> 2;
  const int kb = (wave >> 1) & 1;
  const int dh = wave & 1;
  const int dq = wave & 3;                    // PV role
  const int lane = tid & 63;
  const int l31 = lane & 31, h = lane >> 5;
  const int bid = blockIdx.x;
  const int b = bid & 7;                      // XCD-batch affinity
  const int qb = bid >> 3;                    // 0..31
  const int bN = b * NT2;
  const float scale = 0.044194173824159216f;  // 1/sqrt(512)

  // Q fragments: rows qb*64..+63 live exactly in image qb.
  // qf[j]: frag fk = qg*32 + dh*16 + j -> row = qg*32 + l31, d-chunk dh*256+j*16.
  bf8 qf[16];
  {
    const unsigned short* qimg = W + ((size_t)(bN + qb) << 16);
#pragma unroll
    for (int j = 0; j < 16; ++j)
      qf[j] = *(const bf8*)(qimg + ((qg * 32 + dh * 16 + j) * 64 + lane) * 8);
  }

  // mask -> per-reg row scale for my 8 softmax rows (0 for masked -> p = 1)
  float rs8[8];
  {
    int mv = mask[b * Nn + qb * 64 + qg * 32 + l31];
    unsigned mb = (unsigned)(__ballot(mv != 0) & 0xffffffffull);
#pragma unroll
    for (int ii = 0; ii < 8; ++ii) {
      int i = dh * 8 + ii;
      int row = (i & 3) + 8 * (i >> 2) + 4 * h;
      rs8[ii] = ((mb >> row) & 1u) ? scale : 0.0f;
    }
  }

  bf8 ones;
#pragma unroll
  for (int i = 0; i < 8; ++i) ones[i] = (short)0x3F80;  // bf16 1.0

  f16v o0, o1, o2, o3, lacc;
#pragma unroll
  for (int i = 0; i < 16; ++i) { o0[i] = 0.f; o1[i] = 0.f; o2[i] = 0.f; o3[i] = 0.f; lacc[i] = 0.f; }

  // prologue: stage K image of tile 0 (64 chunks x 1 KB; 8 per wave)
  {
    const unsigned short* img0 = W + ((size_t)bN << 16);
#pragma unroll
    for (int i = 0; i < 8; ++i) {
      int chunk = i * 8 + wave;
      gload_lds16(img0 + chunk * 512 + lane * 8, sK[0] + chunk * 512);
    }
  }
  __syncthreads();

  int cur = 0;
  for (int t = 0; t < NT2; ++t) {
    const unsigned short* sKc = sK[cur];

    // ---- QK^T: S[32q x 32k] partial over d-half, 16 MFMAs (dual chain) ----
    f16v sa, sb;
#pragma unroll
    for (int i = 0; i < 16; ++i) { sa[i] = 0.f; sb[i] = 0.f; }
#pragma unroll
    for (int j2 = 0; j2 < 8; ++j2) {
      bf8 k0 = *(const bf8*)(sKc + ((kb * 32 + dh * 16 + j2 * 2) * 64 + lane) * 8);
      bf8 k1 = *(const bf8*)(sKc + ((kb * 32 + dh * 16 + j2 * 2 + 1) * 64 + lane) * 8);
      sa = __builtin_amdgcn_mfma_f32_32x32x16_bf16(qf[j2 * 2], k0, sa, 0, 0, 0);
      sb = __builtin_amdgcn_mfma_f32_32x32x16_bf16(qf[j2 * 2 + 1], k1, sb, 0, 0, 0);
    }
    // publish partial (bf16; partner consumes the half I don't exp)
#pragma unroll
    for (int i = 0; i < 16; ++i)
      sSx[qg][kb][dh][i][lane] = f2bf(sa[i] + sb[i]);
    __syncthreads();  // barA: partials visible; K reads of buf done

    // ---- wave-local no-max softmax for my 8 rows; P -> sP (disjoint rows) ----
#pragma unroll
    for (int ii = 0; ii < 8; ++ii) {
      int i = dh * 8 + ii;
      float e = (sa[i] + sb[i] + bf2f(sSx[qg][kb][dh ^ 1][i][lane])) * rs8[ii];
      int row = (i & 3) + 8 * (i >> 2) + 4 * h;
      sP[qg][row][kb * 32 + l31] = f2bf(__expf(e));
    }
    __syncthreads();  // barB: full P visible

    // issue next K image (drains at barC under PV cover)
    if (t + 1 < NT2) {
      const unsigned short* gKn = W + ((size_t)(bN + t + 1) << 16);
      unsigned short* nb = sK[cur ^ 1];
#pragma unroll
      for (int i = 0; i < 8; ++i) {
        int chunk = i * 8 + wave;
        gload_lds16(gKn + chunk * 512 + lane * 8, nb + chunk * 512);
      }
    }

    // ---- PV: af[4] (A-layout row=l31, keys m*16+h*8+e); V from L2 ----
    bf8 af[4];
#pragma unroll
    for (int m = 0; m < 4; ++m)
      af[m] = *(const bf8*)(&sP[qg][l31][m * 16 + h * 8]);
#pragma unroll
    for (int m = 0; m < 4; ++m)
      lacc = __builtin_amdgcn_mfma_f32_32x32x16_bf16(af[m], ones, lacc, 0, 0, 0);

    const unsigned short* gV = W + ((size_t)(bN + t) << 16) + 32768;
#pragma unroll
    for (int m = 0; m < 4; ++m) {
      bf8 v0 = *(const bf8*)(gV + (((dq * 4 + 0) * 4 + m) * 64 + lane) * 8);
      bf8 v1 = *(const bf8*)(gV + (((dq * 4 + 1) * 4 + m) * 64 + lane) * 8);
      bf8 v2 = *(const bf8*)(gV + (((dq * 4 + 2) * 4 + m) * 64 + lane) * 8);
      bf8 v3 = *(const bf8*)(gV + (((dq * 4 + 3) * 4 + m) * 64 + lane) * 8);
      o0 = __builtin_amdgcn_mfma_f32_32x32x16_bf16(af[m], v0, o0, 0, 0, 0);
      o1 = __builtin_amdgcn_mfma_f32_32x32x16_bf16(af[m], v1, o1, 0, 0, 0);
      o2 = __builtin_amdgcn_mfma_f32_32x32x16_bf16(af[m], v2, o2, 0, 0, 0);
      o3 = __builtin_amdgcn_mfma_f32_32x32x16_bf16(af[m], v3, o3, 0, 0, 0);
    }
    __syncthreads();  // barC: prefetch drained; sP reads settled
    cur ^= 1;
  }

  // ---- epilogue: normalize by lacc (same reg<->row map), store f32 ----
#pragma unroll
  for (int i = 0; i < 16; ++i) {
    int row = (i & 3) + 8 * (i >> 2) + 4 * h;
    size_t gr = (size_t)b * Nn + qb * 64 + qg * 32 + row;
    float inv = 1.0f / lacc[i];
    out[gr * Dd + dq * 128 + 0 * 32 + l31] = o0[i] * inv;
    out[gr * Dd + dq * 128 + 1 * 32 + l31] = o1[i] * inv;
    out[gr * Dd + dq * 128 + 2 * 32 + l31] = o2[i] * inv;
    out[gr * Dd + dq * 128 + 3 * 32 + l31] = o3[i] * inv;
  }
}

// ---------------------------------------------------------------------------
// Fallback (no usable ws): R10 structure, KV=64, in-kernel convert.
// ---------------------------------------------------------------------------
__global__ __launch_bounds__(256, 1)
void attn_fb(const float* __restrict__ Xf, const int* __restrict__ mask,
             float* __restrict__ out) {
  __shared__ unsigned short sKf[KVF * Dd];
  __shared__ unsigned short sVt[Dd * KVF];
  __shared__ unsigned short sPf[4][16 * PPF];

  const int tid  = threadIdx.x;
  const int wave = tid >> 6, lane = tid & 63;
  const int lg = lane >> 4, ll = lane & 15;
  const int b  = blockIdx.y;
  const int q0 = blockIdx.x * 64 + wave * 16;

  bf8 qf[16];
  {
    const size_t qoff = ((size_t)b * Nn + q0 + ll) * Dd;
#pragma unroll
    for (int ch = 0; ch < 16; ++ch) {
      int doff = ch * 32 + lg * 8;
      float4 a = *(const float4*)(Xf + qoff + doff);
      float4 c = *(const float4*)(Xf + qoff + doff + 4);
      bf8 tt;
      tt[0] = (short)f2bf(a.x); tt[1] = (short)f2bf(a.y);
      tt[2] = (short)f2bf(a.z); tt[3] = (short)f2bf(a.w);
      tt[4] = (short)f2bf(c.x); tt[5] = (short)f2bf(c.y);
      tt[6] = (short)f2bf(c.z); tt[7] = (short)f2bf(c.w);
      qf[ch] = tt;
    }
  }
  float bias[4];
#pragma unroll
  for (int r = 0; r < 4; ++r)
    bias[r] = (1.0f - (float)mask[b * Nn + q0 + lg * 4 + r]) * 1e9f;
  float m[4], lsum[4];
  f4 o[32];
#pragma unroll
  for (int r = 0; r < 4; ++r) { m[r] = -1e30f; lsum[r] = 0.0f; }
#pragma unroll
  for (int ct = 0; ct < 32; ++ct) o[ct] = (f4){0.f, 0.f, 0.f, 0.f};
  const float scale = 0.044194173824159216f;

  for (int t = 0; t < NTF; ++t) {
    __syncthreads();
    const size_t base = ((size_t)b * Nn + t * KVF) * Dd;
#pragma unroll
    for (int it = 0; it < 16; ++it) {
      int idx = it * 256 + tid;
      int key = idx >> 6, c = idx & 63;
      const float* sp = Xf + base + key * Dd + c * 8;
      float4 a = *(const float4*)(sp);
      float4 d2 = *(const float4*)(sp + 4);
      U8 v;
      v.s[0] = f2bf(a.x); v.s[1] = f2bf(a.y); v.s[2] = f2bf(a.z); v.s[3] = f2bf(a.w);
      v.s[4] = f2bf(d2.x); v.s[5] = f2bf(d2.y); v.s[6] = f2bf(d2.z); v.s[7] = f2bf(d2.w);
      *(U8*)(sKf + key * 512 + ((c ^ (key & 7)) << 3)) = v;
      int ko = key >> 3, k7 = key & 7;
#pragma unroll
      for (int j = 0; j < 8; ++j) {
        int dd = c * 8 + j;
        sVt[dd * 64 + ((ko ^ j ^ (c & 7)) << 3) + k7] = v.s[j];
      }
    }
    __syncthreads();

    f4 s[4];
#pragma unroll
    for (int cc = 0; cc < 4; ++cc) s[cc] = (f4){0.f, 0.f, 0.f, 0.f};
#pragma unroll
    for (int ch = 0; ch < 16; ++ch)
#pragma unroll
      for (int cc = 0; cc < 4; ++cc) {
        int key = cc * 16 + ll;
        bf8 kf = *(const bf8*)(sKf + key * 512 + (((ch * 4 + lg) ^ (key & 7)) << 3));
        s[cc] = __builtin_amdgcn_mfma_f32_16x16x32_bf16(qf[ch], kf, s[cc], 0, 0, 0);
      }

    float e[4][4];
#pragma unroll
    for (int cc = 0; cc < 4; ++cc)
#pragma unroll
      for (int r = 0; r < 4; ++r) e[cc][r] = s[cc][r] * scale - bias[r];
    float tm[4];
#pragma unroll
    for (int r = 0; r < 4; ++r)
      tm[r] = fmaxf(fmaxf(e[0][r], e[1][r]), fmaxf(e[2][r], e[3][r]));
#pragma unroll
    for (int off = 1; off < 16; off <<= 1)
#pragma unroll
      for (int r = 0; r < 4; ++r) tm[r] = fmaxf(tm[r], __shfl_xor(tm[r], off));
    float mn[4]; bool change = false;
#pragma unroll
    for (int r = 0; r < 4; ++r) { mn[r] = fmaxf(m[r], tm[r]); change = change || (mn[r] > m[r]); }
    if (__any(change)) {
#pragma unroll
      for (int r = 0; r < 4; ++r) {
        float al = __expf(m[r] - mn[r]);
        lsum[r] *= al; m[r] = mn[r];
#pragma unroll
        for (int ct = 0; ct < 32; ++ct) o[ct][r] *= al;
      }
    }
    float ts[4] = {0.f, 0.f, 0.f, 0.f};
    unsigned short pb[4][4];
#pragma unroll
    for (int cc = 0; cc < 4; ++cc)
#pragma unroll
      for (int r = 0; r < 4; ++r) {
        float p = __expf(e[cc][r] - m[r]);
        ts[r] += p; pb[cc][r] = f2bf(p);
      }
#pragma unroll
    for (int off = 1; off < 16; off <<= 1)
#pragma unroll
      for (int r = 0; r < 4; ++r) ts[r] += __shfl_xor(ts[r], off);
#pragma unroll
    for (int r = 0; r < 4; ++r) lsum[r] += ts[r];

    unsigned short* Pw = sPf[wave];
#pragma unroll
    for (int cc = 0; cc < 4; ++cc)
#pragma unroll
      for (int r = 0; r < 4; ++r)
        Pw[(lg * 4 + r) * PPF + cc * 16 + ll] = pb[cc][r];
#pragma unroll
    for (int kc = 0; kc < 2; ++kc) {
      bf8 af = *(const bf8*)(Pw + ll * PPF + kc * 32 + lg * 8);
#pragma unroll
      for (int ct = 0; ct < 32; ++ct) {
        int d = ct * 16 + ll;
        bf8 vf = *(const bf8*)(sVt + d * 64 + (((kc * 4 + lg) ^ (d & 7) ^ ((d >> 3) & 7)) << 3));
        o[ct] = __builtin_amdgcn_mfma_f32_16x16x32_bf16(af, vf, o[ct], 0, 0, 0);
      }
    }
  }
  float inv[4];
#pragma unroll
  for (int r = 0; r < 4; ++r) inv[r] = 1.0f / lsum[r];
#pragma unroll
  for (int ct = 0; ct < 32; ++ct)
#pragma unroll
    for (int r = 0; r < 4; ++r) {
      size_t row = (size_t)b * Nn + q0 + lg * 4 + r;
      out[row * Dd + ct * 16 + ll] = o[ct][r] * inv[r];
    }
}

extern "C" void kernel_launch(void* const* d_in, const int* in_sizes, int n_in,
                              void* d_out, int out_size, void* d_ws, size_t ws_size,
                              hipStream_t stream) {
  (void)in_sizes; (void)n_in; (void)out_size;
  const float* X  = (const float*)d_in[0];
  const int* mask = (const int*)d_in[1];
  float* out = (float*)d_out;

  const size_t szImg = (size_t)Bb * NT2 * 131072;  // 32 MiB of bf16 images
  if (ws_size >= szImg) {
    unsigned short* W = (unsigned short*)d_ws;
    build_images<<<dim3(NT2, Bb), 256, 0, stream>>>(X, W);
    attn64<<<256, 512, 0, stream>>>(W, mask, out);
  } else {
    attn_fb<<<dim3(Nn / 64, Bb), 256, 0, stream>>>(X, mask, out);
  }
}